// Round 6
// baseline (654.233 us; speedup 1.0000x reference)
//
#include <hip/hip_runtime.h>
#include <hip/hip_bf16.h>
#include <cstdint>
#include <cstddef>

#define TEXT_H_   4096
#define S_TOK     4096
#define P_TOK     1024
#define ROWS_PB   3072            // rows per batch after dropping s<1024
#define M_ROWS    6144            // 2 * 3072
#define NK        4096            // N and K of both GEMMs

// GEMM geometry: 128x256 tile, BK=64, 8 waves (2Mx4N), 512 threads, 3-slot LDS ring
#define BM        128
#define BN        256
#define BK        64
#define NT        (NK / BK)            // 64 K-tiles
#define GRID_M    (M_ROWS / BM)        // 48
#define GRID_N    (NK / BN)            // 16
#define NWG       (GRID_M * GRID_N)    // 768 blocks = 3 perfect rounds on 256 CUs
#define A_CHUNKS  (BM * BK * 2 / 1024) // 16
#define SLOT_CHUNKS ((BM + BN) * BK * 2 / 1024)  // 48
#define SLOT_BYTES  (SLOT_CHUNKS * 1024)         // 49152
#define LDS_TOTAL   (3 * SLOT_BYTES)             // 147456

typedef __attribute__((ext_vector_type(8))) short  bf16x8_t;
typedef __attribute__((ext_vector_type(4))) float  f32x4_t;
typedef __attribute__((ext_vector_type(4))) float  fl4_t;
typedef __attribute__((ext_vector_type(4))) ushort u16x4_t;
typedef __attribute__((ext_vector_type(8))) ushort u16x8_t;

__device__ int g_mask_isbool;

__device__ __forceinline__ ushort f2bf(float f) {
  uint32_t u = __float_as_uint(f);
  u += 0x7FFFu + ((u >> 16) & 1u);
  return (ushort)(u >> 16);
}

__device__ __forceinline__ void gload_lds16(const void* g, void* l) {
  __builtin_amdgcn_global_load_lds((const __attribute__((address_space(1))) void*)g,
                                   (__attribute__((address_space(3))) void*)l, 16, 0, 0);
}

__global__ void detect_mask_kernel(const unsigned* __restrict__ mask) {
  if (threadIdx.x == 0) {
    int isbool = 0;
    for (int i = 0; i < 64; ++i)
      if (mask[i] & ~1u) isbool = 1;
    g_mask_isbool = isbool;
  }
}

// ---------------- pre-pass: x rows (s>=1024) f32 -> bf16, dense [6144][4096] ----------------
__global__ void convert_x_kernel(const float* __restrict__ x, ushort* __restrict__ A1) {
  const int m = blockIdx.x;
  const int bb = (m >= ROWS_PB) ? 1 : 0;
  const int s  = P_TOK + (m - bb * ROWS_PB);
  const float* src = x + ((size_t)bb * S_TOK + s) * TEXT_H_;
  ushort* dst = A1 + (size_t)m * TEXT_H_;
  const int t = threadIdx.x;
#pragma unroll
  for (int c = 0; c < 2; ++c) {
    const int base = t * 16 + c * 8;
    fl4_t f0 = *(const fl4_t*)(src + base);
    fl4_t f1 = *(const fl4_t*)(src + base + 4);
    u16x8_t o;
    o[0] = f2bf(f0[0]); o[1] = f2bf(f0[1]); o[2] = f2bf(f0[2]); o[3] = f2bf(f0[3]);
    o[4] = f2bf(f1[0]); o[5] = f2bf(f1[1]); o[6] = f2bf(f1[2]); o[7] = f2bf(f1[3]);
    *(u16x8_t*)(dst + base) = o;
  }
}

// ---------------- pre-pass: W [K][N] f32 -> W^T [N][K] bf16 (64x64 LDS tile) ----------------
__global__ void transpose_w_kernel(const float* __restrict__ W, ushort* __restrict__ WT) {
  __shared__ float tile[64][65];
  const int kb = blockIdx.x * 64;
  const int nb = blockIdx.y * 64;
  const int t  = threadIdx.x;
  const int lr = t >> 4;
  const int lc = (t & 15) * 4;
#pragma unroll
  for (int it = 0; it < 4; ++it) {
    const int row = lr + it * 16;
    fl4_t v = *(const fl4_t*)(W + (size_t)(kb + row) * NK + nb + lc);
    tile[row][lc + 0] = v[0]; tile[row][lc + 1] = v[1];
    tile[row][lc + 2] = v[2]; tile[row][lc + 3] = v[3];
  }
  __syncthreads();
#pragma unroll
  for (int it = 0; it < 4; ++it) {
    const int n = lr + it * 16;
    u16x4_t o;
    o[0] = f2bf(tile[lc + 0][n]); o[1] = f2bf(tile[lc + 1][n]);
    o[2] = f2bf(tile[lc + 2][n]); o[3] = f2bf(tile[lc + 3][n]);
    *(u16x4_t*)(WT + (size_t)(nb + n) * NK + kb + lc) = o;
  }
}

// Stage one K-tile (48 x 1KB fragment-order chunks, 6 per wave).
// chunk c (A: c<16, B: c-16): lane l supplies
//   G[base + (c>>1)*16 + (l&15)][kt + (c&1)*32 + (l>>4)*8 .. +7]
// landing at slot + c*1024 + l*16 (linear dest, pre-permuted global source).
__device__ __forceinline__ void stage_tile(const ushort* __restrict__ A,
                                           const ushort* __restrict__ Bt,
                                           int row0, int col0, char* slot,
                                           int kt, int w, int l) {
#pragma unroll
  for (int i = 0; i < 6; ++i) {
    const int c = w * 6 + i;
    const ushort* src;
    if (c < A_CHUNKS) {
      src = A  + (size_t)(row0 + (c >> 1) * 16 + (l & 15)) * NK
               + kt + (c & 1) * 32 + (l >> 4) * 8;
    } else {
      const int cb = c - A_CHUNKS;
      src = Bt + (size_t)(col0 + (cb >> 1) * 16 + (l & 15)) * NK
               + kt + (cb & 1) * 32 + (l >> 4) * 8;
    }
    gload_lds16(src, slot + c * 1024 + l * 16);
  }
}

// ---------------- GEMM: C[M][4096] = A[M][4096] * Bt[4096][4096]^T, fused epilogue ----------
// MODE 0: Hout[r][c] = bf16(gelu(acc + bias[c]))
// MODE 1: Yout[r][c] = mask_row ? f32(acc + bias[c]) : 0   (d_out is FLOAT32)
template <int MODE>
__launch_bounds__(512, 2)
__global__ void gemm_bf16_kernel(const ushort* __restrict__ A, const ushort* __restrict__ Bt,
                                 const float* __restrict__ bias, const void* __restrict__ mask,
                                 ushort* __restrict__ Hout, float* __restrict__ Yout) {
  extern __shared__ char lds[];

  const int tid = threadIdx.x;
  const int l   = tid & 63;
  const int w   = tid >> 6;       // 0..7
  const int wr  = w >> 2;         // 0..1 (M)
  const int wc  = w & 3;          // 0..3 (N)

  int bid = blockIdx.x;
  bid = (bid & 7) * (NWG / 8) + (bid >> 3);   // XCD swizzle (NWG % 8 == 0 -> bijective)
  const int row0 = (bid >> 4) * BM;
  const int col0 = (bid & 15) * BN;

  f32x4_t acc[4][4] = {};

  // prologue: stage tiles 0 and 1 into slots 0 and 1 (6 loads each per wave)
  stage_tile(A, Bt, row0, col0, lds,              0,  w, l);
  stage_tile(A, Bt, row0, col0, lds + SLOT_BYTES, BK, w, l);

  int s_cur = 0;                  // slot of tile t
  int s_stage = 2;                // slot of tile t+2

  for (int t = 0; t < NT; ++t) {
    // own tile-t loads done (tile t+1's 6 stay in flight); then cross-wave barrier:
    // all waves' tile-t loads landed AND all waves finished reading tile t-1
    // (their reads were lgkm-waited before their iter-(t-1) MFMAs) -> slot(t+2)
    // = slot(t-1) is safe to restage.
    if (t == NT - 1) asm volatile("s_waitcnt vmcnt(0)" ::: "memory");
    else             asm volatile("s_waitcnt vmcnt(6)" ::: "memory");
    __builtin_amdgcn_sched_barrier(0);
    __builtin_amdgcn_s_barrier();
    __builtin_amdgcn_sched_barrier(0);

    // fire-and-forget: stage tile t+2 (lands within ~2 iterations)
    if (t + 2 < NT)
      stage_tile(A, Bt, row0, col0, lds + s_stage * SLOT_BYTES, (t + 2) * BK, w, l);

    const char* Ab = lds + s_cur * SLOT_BYTES;

    bf16x8_t af[4][2], bf[4][2];
#pragma unroll
    for (int ni = 0; ni < 4; ++ni)
#pragma unroll
      for (int kk = 0; kk < 2; ++kk)
        bf[ni][kk] = *(const bf16x8_t*)(Ab + ((A_CHUNKS + (wc * 4 + ni) * 2 + kk) << 10) + l * 16);
#pragma unroll
    for (int mi = 0; mi < 4; ++mi)
#pragma unroll
      for (int kk = 0; kk < 2; ++kk)
        af[mi][kk] = *(const bf16x8_t*)(Ab + (((wr * 4 + mi) * 2 + kk) << 10) + l * 16);

    __builtin_amdgcn_s_setprio(1);
#pragma unroll
    for (int mi = 0; mi < 4; ++mi)
#pragma unroll
      for (int ni = 0; ni < 4; ++ni)
#pragma unroll
        for (int kk = 0; kk < 2; ++kk)
          acc[mi][ni] = __builtin_amdgcn_mfma_f32_16x16x32_bf16(af[mi][kk], bf[ni][kk],
                                                                acc[mi][ni], 0, 0, 0);
    __builtin_amdgcn_s_setprio(0);

    s_cur   = (s_cur   == 2) ? 0 : s_cur + 1;
    s_stage = (s_stage == 2) ? 0 : s_stage + 1;
  }

  const int isbool = (MODE == 1) ? g_mask_isbool : 0;

  // epilogue: D col = lane&15, row = (lane>>4)*4 + j  (round-3/5-verified)
#pragma unroll
  for (int mi = 0; mi < 4; ++mi) {
#pragma unroll
    for (int j = 0; j < 4; ++j) {
      const int r = row0 + wr * 64 + mi * 16 + (l >> 4) * 4 + j;
      if (MODE == 0) {
#pragma unroll
        for (int ni = 0; ni < 4; ++ni) {
          const int c = col0 + wc * 64 + ni * 16 + (l & 15);
          float v = acc[mi][ni][j] + bias[c];
          v = 0.5f * v * (1.0f + erff(v * 0.70710678118654752f));
          Hout[(size_t)r * NK + c] = f2bf(v);
        }
      } else {
        const int bb  = (r >= ROWS_PB) ? 1 : 0;
        const int sm  = r - bb * ROWS_PB;
        const int idx = bb * S_TOK + P_TOK + sm;
        const int mk  = isbool ? (int)((const unsigned char*)mask)[idx]
                               : ((const int*)mask)[idx];
#pragma unroll
        for (int ni = 0; ni < 4; ++ni) {
          const int c = col0 + wc * 64 + ni * 16 + (l & 15);
          const float v = acc[mi][ni][j] + bias[c];
          Yout[(size_t)r * NK + c] = mk ? v : 0.0f;
        }
      }
    }
  }
}

extern "C" void kernel_launch(void* const* d_in, const int* in_sizes, int n_in,
                              void* d_out, int out_size, void* d_ws, size_t ws_size,
                              hipStream_t stream) {
  const float* x     = (const float*)d_in[0];
  const void*  tmask = (const void*)d_in[1];
  // d_in[2] = prefix_mask (shape known: prefix_len = 4096 rows dropped)
  const float* W1    = (const float*)d_in[3];
  const float* b1    = (const float*)d_in[4];
  const float* W2    = (const float*)d_in[5];
  const float* b2    = (const float*)d_in[6];
  float* out = (float*)d_out;   // reference output dtype is float32

  const size_t offA1  = 0;
  const size_t offB1T = offA1  + (size_t)M_ROWS * NK * 2;   // 48 MiB
  const size_t offB2T = offB1T + (size_t)NK * NK * 2;       // +32 MiB
  const size_t offH   = offB2T + (size_t)NK * NK * 2;       // +32 MiB
  const size_t need   = offH   + (size_t)M_ROWS * NK * 2;   // +48 MiB = 160 MiB
  if (ws_size < need) return;

  char* ws = (char*)d_ws;
  ushort* A1  = (ushort*)(ws + offA1);
  ushort* B1T = (ushort*)(ws + offB1T);
  ushort* B2T = (ushort*)(ws + offB2T);
  ushort* H   = (ushort*)(ws + offH);

  detect_mask_kernel<<<1, 64, 0, stream>>>((const unsigned*)tmask);
  convert_x_kernel<<<dim3(M_ROWS), 256, 0, stream>>>(x, A1);
  transpose_w_kernel<<<dim3(64, 64), 256, 0, stream>>>(W1, B1T);
  transpose_w_kernel<<<dim3(64, 64), 256, 0, stream>>>(W2, B2T);
  gemm_bf16_kernel<0><<<dim3(NWG), dim3(512), LDS_TOTAL, stream>>>(A1, B1T, b1, nullptr, H, nullptr);
  gemm_bf16_kernel<1><<<dim3(NWG), dim3(512), LDS_TOTAL, stream>>>(H, B2T, b2, tmask, nullptr, out);
}

// Round 7
// 606.805 us; speedup vs baseline: 1.0782x; 1.0782x over previous
//
#include <hip/hip_runtime.h>
#include <hip/hip_bf16.h>
#include <cstdint>
#include <cstddef>

#define TEXT_H_   4096
#define S_TOK     4096
#define P_TOK     1024
#define ROWS_PB   3072            // rows per batch after dropping s<1024
#define M_ROWS    6144            // 2 * 3072
#define NK        4096            // N and K of both GEMMs

// GEMM geometry: 256x256 tile, BK=64, 8 waves (2Mx4N), 512 threads, 8-phase schedule
#define BM        256
#define BN        256
#define BK        64
#define NT        (NK / BK)            // 64 K-tiles
#define GRID_M    (M_ROWS / BM)        // 24
#define GRID_N    (NK / BN)            // 16
#define NWG       (GRID_M * GRID_N)    // 384
#define SLOT_BYTES  (64 * 1024)        // A 32KB (chunks 0-31) + B 32KB (chunks 32-63)
#define LDS_TOTAL   (2 * SLOT_BYTES)   // 128 KiB

typedef __attribute__((ext_vector_type(8))) short  bf16x8_t;
typedef __attribute__((ext_vector_type(4))) float  f32x4_t;
typedef __attribute__((ext_vector_type(4))) float  fl4_t;
typedef __attribute__((ext_vector_type(4))) ushort u16x4_t;
typedef __attribute__((ext_vector_type(8))) ushort u16x8_t;

__device__ int g_mask_isbool;

__device__ __forceinline__ ushort f2bf(float f) {
  uint32_t u = __float_as_uint(f);
  u += 0x7FFFu + ((u >> 16) & 1u);
  return (ushort)(u >> 16);
}

__device__ __forceinline__ void gload_lds16(const void* g, void* l) {
  __builtin_amdgcn_global_load_lds((const __attribute__((address_space(1))) void*)g,
                                   (__attribute__((address_space(3))) void*)l, 16, 0, 0);
}

#define BAR()   do { __builtin_amdgcn_sched_barrier(0); __builtin_amdgcn_s_barrier(); \
                     __builtin_amdgcn_sched_barrier(0); } while (0)
#define LGKM0() do { asm volatile("s_waitcnt lgkmcnt(0)" ::: "memory"); \
                     __builtin_amdgcn_sched_barrier(0); } while (0)

__global__ void detect_mask_kernel(const unsigned* __restrict__ mask) {
  if (threadIdx.x == 0) {
    int isbool = 0;
    for (int i = 0; i < 64; ++i)
      if (mask[i] & ~1u) isbool = 1;
    g_mask_isbool = isbool;
  }
}

// ---------------- pre-pass: x rows (s>=1024) f32 -> bf16, dense [6144][4096] ----------------
__global__ void convert_x_kernel(const float* __restrict__ x, ushort* __restrict__ A1) {
  const int m = blockIdx.x;
  const int bb = (m >= ROWS_PB) ? 1 : 0;
  const int s  = P_TOK + (m - bb * ROWS_PB);
  const float* src = x + ((size_t)bb * S_TOK + s) * TEXT_H_;
  ushort* dst = A1 + (size_t)m * TEXT_H_;
  const int t = threadIdx.x;
#pragma unroll
  for (int c = 0; c < 2; ++c) {
    const int base = t * 16 + c * 8;
    fl4_t f0 = *(const fl4_t*)(src + base);
    fl4_t f1 = *(const fl4_t*)(src + base + 4);
    u16x8_t o;
    o[0] = f2bf(f0[0]); o[1] = f2bf(f0[1]); o[2] = f2bf(f0[2]); o[3] = f2bf(f0[3]);
    o[4] = f2bf(f1[0]); o[5] = f2bf(f1[1]); o[6] = f2bf(f1[2]); o[7] = f2bf(f1[3]);
    *(u16x8_t*)(dst + base) = o;
  }
}

// ---------------- pre-pass: W [K][N] f32 -> W^T [N][K] bf16 (64x64 LDS tile) ----------------
__global__ void transpose_w_kernel(const float* __restrict__ W, ushort* __restrict__ WT) {
  __shared__ float tile[64][65];
  const int kb = blockIdx.x * 64;
  const int nb = blockIdx.y * 64;
  const int t  = threadIdx.x;
  const int lr = t >> 4;
  const int lc = (t & 15) * 4;
#pragma unroll
  for (int it = 0; it < 4; ++it) {
    const int row = lr + it * 16;
    fl4_t v = *(const fl4_t*)(W + (size_t)(kb + row) * NK + nb + lc);
    tile[row][lc + 0] = v[0]; tile[row][lc + 1] = v[1];
    tile[row][lc + 2] = v[2]; tile[row][lc + 3] = v[3];
  }
  __syncthreads();
#pragma unroll
  for (int it = 0; it < 4; ++it) {
    const int n = lr + it * 16;
    u16x4_t o;
    o[0] = f2bf(tile[lc + 0][n]); o[1] = f2bf(tile[lc + 1][n]);
    o[2] = f2bf(tile[lc + 2][n]); o[3] = f2bf(tile[lc + 3][n]);
    *(u16x4_t*)(WT + (size_t)(nb + n) * NK + kb + lc) = o;
  }
}

// Chunk layout per 64KB slot: chunk(blk,kk) = 1KB holding rows blk*16..+15,
// k kk*32..+31; lane l <-> row blk*16+(l&15), k +(l>>4)*8 (8 bf16 = 16B).
// A: chunks 0..31 (blk=row/16), B: chunks 32..63 (blk=col/16).
// Stage groups of 16 chunks (2 gload_lds/thread), ordered to match read order:
//   J=0: A chunks {0-7,16-23}   (read in P1 by afL)
//   J=1: B rel    {0-3,8-11,16-19,24-27} (P1, bfL)
//   J=2: B rel    {4-7,12-15,20-23,28-31} (P2, bfH)
//   J=3: A chunks {8-15,24-31}  (P3, afH)
template <int J>
__device__ __forceinline__ void stage_group(const ushort* __restrict__ A,
                                            const ushort* __restrict__ Bt,
                                            int row0, int col0, char* lds,
                                            int tau, int w, int l) {
  char* slot = lds + (tau & 1) * SLOT_BYTES;
  const int kt = tau * BK;
#pragma unroll
  for (int q = 0; q < 2; ++q) {
    const int cg = q * 8 + w;            // wave-uniform chunk-in-group
    if (J == 0 || J == 3) {
      const int CH = (J == 0 ? 0 : 8) + cg + (cg & 8);
      const ushort* src = A + (size_t)(row0 + (CH >> 1) * 16 + (l & 15)) * NK
                            + kt + (CH & 1) * 32 + (l >> 4) * 8;
      gload_lds16(src, slot + CH * 1024 + l * 16);
    } else {
      const int r = (cg >> 2) * 8 + (cg & 3) + (J == 2 ? 4 : 0);
      const ushort* src = Bt + (size_t)(col0 + (r >> 1) * 16 + (l & 15)) * NK
                             + kt + (r & 1) * 32 + (l >> 4) * 8;
      gload_lds16(src, slot + (32 + r) * 1024 + l * 16);
    }
  }
}

// ---------------- GEMM: C[M][4096] = A[M][4096] * Bt[4096][4096]^T, fused epilogue ----------
// MODE 0: Hout[r][c] = bf16(gelu(acc + bias[c]))
// MODE 1: Yout[r][c] = mask_row ? f32(acc + bias[c]) : 0   (d_out is FLOAT32)
template <int MODE>
__launch_bounds__(512, 2)
__global__ void gemm_bf16_kernel(const ushort* __restrict__ A, const ushort* __restrict__ Bt,
                                 const float* __restrict__ bias, const void* __restrict__ mask,
                                 ushort* __restrict__ Hout, float* __restrict__ Yout) {
  extern __shared__ char lds[];

  const int tid = threadIdx.x;
  const int l   = tid & 63;
  const int w   = tid >> 6;       // 0..7
  const int wr  = w >> 2;         // 0..1 (M): rows wr*128 .. +127
  const int wc  = w & 3;          // 0..3 (N): cols wc*64 .. +63

  int bid = blockIdx.x;
  bid = (bid & 7) * (NWG / 8) + (bid >> 3);   // XCD swizzle (384 % 8 == 0 -> bijective)
  const int row0 = (bid >> 4) * BM;
  const int col0 = (bid & 15) * BN;

  f32x4_t acc[8][4] = {};

  // prologue: stage groups 0..6 (tiles 0:j0-3, 1:j0-2) = 14 loads/thread
  stage_group<0>(A, Bt, row0, col0, lds, 0, w, l);
  stage_group<1>(A, Bt, row0, col0, lds, 0, w, l);
  stage_group<2>(A, Bt, row0, col0, lds, 0, w, l);
  stage_group<3>(A, Bt, row0, col0, lds, 0, w, l);
  stage_group<0>(A, Bt, row0, col0, lds, 1, w, l);
  stage_group<1>(A, Bt, row0, col0, lds, 1, w, l);
  stage_group<2>(A, Bt, row0, col0, lds, 1, w, l);
  asm volatile("s_waitcnt vmcnt(4)" ::: "memory");   // groups 0-4 landed
  BAR();

  for (int t = 0; t < NT; ++t) {
    char* s = lds + (t & 1) * SLOT_BYTES;

    // ================ P1: read afL+bfL (12), stage g=4t+7 (tile t+1, J3) ================
    bf16x8_t afL[4][2], bfL[2][2];
#pragma unroll
    for (int mi = 0; mi < 4; ++mi)
#pragma unroll
      for (int kk = 0; kk < 2; ++kk)
        afL[mi][kk] = *(const bf16x8_t*)(s + (2 * (wr * 8 + mi) + kk) * 1024 + l * 16);
#pragma unroll
    for (int ni = 0; ni < 2; ++ni)
#pragma unroll
      for (int kk = 0; kk < 2; ++kk)
        bfL[ni][kk] = *(const bf16x8_t*)(s + (32 + 2 * (wc * 4 + ni) + kk) * 1024 + l * 16);
    if (t + 1 < NT) stage_group<3>(A, Bt, row0, col0, lds, t + 1, w, l);
    asm volatile("s_waitcnt lgkmcnt(8)" ::: "memory");
    BAR();
    LGKM0();
    __builtin_amdgcn_s_setprio(1);
#pragma unroll
    for (int mi = 0; mi < 4; ++mi)
#pragma unroll
      for (int ni = 0; ni < 2; ++ni)
#pragma unroll
        for (int kk = 0; kk < 2; ++kk)
          acc[mi][ni] = __builtin_amdgcn_mfma_f32_16x16x32_bf16(afL[mi][kk], bfL[ni][kk],
                                                                acc[mi][ni], 0, 0, 0);
    __builtin_amdgcn_s_setprio(0);
    BAR();

    // ================ P2: read bfH (4), stage g=4t+8 (tile t+2, J0) ================
    bf16x8_t bfH[2][2];
#pragma unroll
    for (int ni = 0; ni < 2; ++ni)
#pragma unroll
      for (int kk = 0; kk < 2; ++kk)
        bfH[ni][kk] = *(const bf16x8_t*)(s + (32 + 2 * (wc * 4 + 2 + ni) + kk) * 1024 + l * 16);
    if (t + 2 < NT) stage_group<0>(A, Bt, row0, col0, lds, t + 2, w, l);
    BAR();
    LGKM0();
    __builtin_amdgcn_s_setprio(1);
#pragma unroll
    for (int mi = 0; mi < 4; ++mi)
#pragma unroll
      for (int ni = 0; ni < 2; ++ni)
#pragma unroll
        for (int kk = 0; kk < 2; ++kk)
          acc[mi][2 + ni] = __builtin_amdgcn_mfma_f32_16x16x32_bf16(afL[mi][kk], bfH[ni][kk],
                                                                    acc[mi][2 + ni], 0, 0, 0);
    __builtin_amdgcn_s_setprio(0);
    BAR();

    // ================ P3: read afH (8), stage g=4t+9 (tile t+2, J1) ================
    bf16x8_t afH[4][2];
#pragma unroll
    for (int mi = 0; mi < 4; ++mi)
#pragma unroll
      for (int kk = 0; kk < 2; ++kk)
        afH[mi][kk] = *(const bf16x8_t*)(s + (2 * (wr * 8 + 4 + mi) + kk) * 1024 + l * 16);
    if (t + 2 < NT) stage_group<1>(A, Bt, row0, col0, lds, t + 2, w, l);
    BAR();
    LGKM0();
    __builtin_amdgcn_s_setprio(1);
#pragma unroll
    for (int mi = 0; mi < 4; ++mi)
#pragma unroll
      for (int ni = 0; ni < 2; ++ni)
#pragma unroll
        for (int kk = 0; kk < 2; ++kk)
          acc[4 + mi][2 + ni] = __builtin_amdgcn_mfma_f32_16x16x32_bf16(afH[mi][kk], bfH[ni][kk],
                                                                        acc[4 + mi][2 + ni], 0, 0, 0);
    __builtin_amdgcn_s_setprio(0);
    BAR();

    // ================ P4: stage g=4t+10 (tile t+2, J2), counted vmcnt ================
    if (t + 2 < NT) stage_group<2>(A, Bt, row0, col0, lds, t + 2, w, l);
    if (t >= NT - 2) asm volatile("s_waitcnt vmcnt(0)" ::: "memory");
    else             asm volatile("s_waitcnt vmcnt(4)" ::: "memory");
    BAR();
    __builtin_amdgcn_s_setprio(1);
#pragma unroll
    for (int mi = 0; mi < 4; ++mi)
#pragma unroll
      for (int ni = 0; ni < 2; ++ni)
#pragma unroll
        for (int kk = 0; kk < 2; ++kk)
          acc[4 + mi][ni] = __builtin_amdgcn_mfma_f32_16x16x32_bf16(afH[mi][kk], bfL[ni][kk],
                                                                    acc[4 + mi][ni], 0, 0, 0);
    __builtin_amdgcn_s_setprio(0);
    BAR();
  }

  const int isbool = (MODE == 1) ? g_mask_isbool : 0;

  // epilogue: D col = lane&15, row = (lane>>4)*4 + j  (round-3/5-verified)
#pragma unroll
  for (int mi = 0; mi < 8; ++mi) {
#pragma unroll
    for (int j = 0; j < 4; ++j) {
      const int r = row0 + wr * 128 + mi * 16 + (l >> 4) * 4 + j;
      if (MODE == 0) {
#pragma unroll
        for (int ni = 0; ni < 4; ++ni) {
          const int c = col0 + wc * 64 + ni * 16 + (l & 15);
          float v = acc[mi][ni][j] + bias[c];
          v = 0.5f * v * (1.0f + erff(v * 0.70710678118654752f));
          Hout[(size_t)r * NK + c] = f2bf(v);
        }
      } else {
        const int bb  = (r >= ROWS_PB) ? 1 : 0;
        const int sm  = r - bb * ROWS_PB;
        const int idx = bb * S_TOK + P_TOK + sm;
        const int mk  = isbool ? (int)((const unsigned char*)mask)[idx]
                               : ((const int*)mask)[idx];
#pragma unroll
        for (int ni = 0; ni < 4; ++ni) {
          const int c = col0 + wc * 64 + ni * 16 + (l & 15);
          const float v = acc[mi][ni][j] + bias[c];
          Yout[(size_t)r * NK + c] = mk ? v : 0.0f;
        }
      }
    }
  }
}

extern "C" void kernel_launch(void* const* d_in, const int* in_sizes, int n_in,
                              void* d_out, int out_size, void* d_ws, size_t ws_size,
                              hipStream_t stream) {
  const float* x     = (const float*)d_in[0];
  const void*  tmask = (const void*)d_in[1];
  // d_in[2] = prefix_mask (shape known: prefix_len = 4096 rows dropped)
  const float* W1    = (const float*)d_in[3];
  const float* b1    = (const float*)d_in[4];
  const float* W2    = (const float*)d_in[5];
  const float* b2    = (const float*)d_in[6];
  float* out = (float*)d_out;   // reference output dtype is float32

  const size_t offA1  = 0;
  const size_t offB1T = offA1  + (size_t)M_ROWS * NK * 2;   // 48 MiB
  const size_t offB2T = offB1T + (size_t)NK * NK * 2;       // +32 MiB
  const size_t offH   = offB2T + (size_t)NK * NK * 2;       // +32 MiB
  const size_t need   = offH   + (size_t)M_ROWS * NK * 2;   // +48 MiB = 160 MiB
  if (ws_size < need) return;

  char* ws = (char*)d_ws;
  ushort* A1  = (ushort*)(ws + offA1);
  ushort* B1T = (ushort*)(ws + offB1T);
  ushort* B2T = (ushort*)(ws + offB2T);
  ushort* H   = (ushort*)(ws + offH);

  detect_mask_kernel<<<1, 64, 0, stream>>>((const unsigned*)tmask);
  convert_x_kernel<<<dim3(M_ROWS), 256, 0, stream>>>(x, A1);
  transpose_w_kernel<<<dim3(64, 64), 256, 0, stream>>>(W1, B1T);
  transpose_w_kernel<<<dim3(64, 64), 256, 0, stream>>>(W2, B2T);
  gemm_bf16_kernel<0><<<dim3(NWG), dim3(512), LDS_TOTAL, stream>>>(A1, B1T, b1, nullptr, H, nullptr);
  gemm_bf16_kernel<1><<<dim3(NWG), dim3(512), LDS_TOTAL, stream>>>(H, B2T, b2, tmask, nullptr, out);
}

// Round 9
// 547.780 us; speedup vs baseline: 1.1943x; 1.1078x over previous
//
#include <hip/hip_runtime.h>
#include <hip/hip_bf16.h>
#include <cstdint>
#include <cstddef>

#define TEXT_H_   4096
#define S_TOK     4096
#define P_TOK     1024
#define ROWS_PB   3072            // rows per batch after dropping s<1024
#define M_ROWS    6144            // 2 * 3072
#define NK        4096            // N and K of both GEMMs
#define BK        64
#define NT        (NK / BK)       // 64 K-tiles

// band0: rows 0..4095, 256x256 tile, 8 waves, 4-phase/K-tile, 128KB LDS, grid 256
#define BM0       256
#define BN        256
#define NWG0      256
#define SLOT0_BYTES (64 * 1024)
#define LDS0_TOTAL  (2 * SLOT0_BYTES)
// band1: rows 4096..6143, 128x256 tile, 8 waves, 2-phase/K-tile, 96KB LDS, grid 256
#define BM1       128
#define ROW_BASE1 4096
#define NWG1      256
#define SLOT1_BYTES (48 * 1024)
#define LDS1_TOTAL  (2 * SLOT1_BYTES)

typedef __attribute__((ext_vector_type(8))) short  bf16x8_t;
typedef __attribute__((ext_vector_type(4))) float  f32x4_t;
typedef __attribute__((ext_vector_type(4))) float  fl4_t;
typedef __attribute__((ext_vector_type(4))) ushort u16x4_t;
typedef __attribute__((ext_vector_type(8))) ushort u16x8_t;

__device__ int g_mask_isbool;

__device__ __forceinline__ ushort f2bf(float f) {
  uint32_t u = __float_as_uint(f);
  u += 0x7FFFu + ((u >> 16) & 1u);
  return (ushort)(u >> 16);
}

__device__ __forceinline__ void gload_lds16(const void* g, void* l) {
  __builtin_amdgcn_global_load_lds((const __attribute__((address_space(1))) void*)g,
                                   (__attribute__((address_space(3))) void*)l, 16, 0, 0);
}

// Raw barrier / waits: "memory" clobber orders all memory ops (ds_read, gload_lds)
// across them, but leaves MFMA/VALU free for the compiler to interleave.
// Protocol invariant: every per-wave vmcnt guarantee is followed by a BARRIER
// before any other wave reads the staged data (vmcnt is per-wave).
#define BARRIER()    asm volatile("s_barrier" ::: "memory")
#define WAIT_LGKM(n) asm volatile("s_waitcnt lgkmcnt(" #n ")" ::: "memory")
#define WAIT_VM(n)   asm volatile("s_waitcnt vmcnt(" #n ")" ::: "memory")

__global__ void detect_mask_kernel(const unsigned* __restrict__ mask) {
  if (threadIdx.x == 0) {
    int isbool = 0;
    for (int i = 0; i < 64; ++i)
      if (mask[i] & ~1u) isbool = 1;
    g_mask_isbool = isbool;
  }
}

// ---------------- pre-pass: x rows (s>=1024) f32 -> bf16, dense [6144][4096] ----------------
__global__ void convert_x_kernel(const float* __restrict__ x, ushort* __restrict__ A1) {
  const int m = blockIdx.x;
  const int bb = (m >= ROWS_PB) ? 1 : 0;
  const int s  = P_TOK + (m - bb * ROWS_PB);
  const float* src = x + ((size_t)bb * S_TOK + s) * TEXT_H_;
  ushort* dst = A1 + (size_t)m * TEXT_H_;
  const int t = threadIdx.x;
#pragma unroll
  for (int c = 0; c < 2; ++c) {
    const int base = t * 16 + c * 8;
    fl4_t f0 = *(const fl4_t*)(src + base);
    fl4_t f1 = *(const fl4_t*)(src + base + 4);
    u16x8_t o;
    o[0] = f2bf(f0[0]); o[1] = f2bf(f0[1]); o[2] = f2bf(f0[2]); o[3] = f2bf(f0[3]);
    o[4] = f2bf(f1[0]); o[5] = f2bf(f1[1]); o[6] = f2bf(f1[2]); o[7] = f2bf(f1[3]);
    *(u16x8_t*)(dst + base) = o;
  }
}

// ---------------- pre-pass: W [K][N] f32 -> W^T [N][K] bf16 (64x64 LDS tile) ----------------
__global__ void transpose_w_kernel(const float* __restrict__ W, ushort* __restrict__ WT) {
  __shared__ float tile[64][65];
  const int kb = blockIdx.x * 64;
  const int nb = blockIdx.y * 64;
  const int t  = threadIdx.x;
  const int lr = t >> 4;
  const int lc = (t & 15) * 4;
#pragma unroll
  for (int it = 0; it < 4; ++it) {
    const int row = lr + it * 16;
    fl4_t v = *(const fl4_t*)(W + (size_t)(kb + row) * NK + nb + lc);
    tile[row][lc + 0] = v[0]; tile[row][lc + 1] = v[1];
    tile[row][lc + 2] = v[2]; tile[row][lc + 3] = v[3];
  }
  __syncthreads();
#pragma unroll
  for (int it = 0; it < 4; ++it) {
    const int n = lr + it * 16;
    u16x4_t o;
    o[0] = f2bf(tile[lc + 0][n]); o[1] = f2bf(tile[lc + 1][n]);
    o[2] = f2bf(tile[lc + 2][n]); o[3] = f2bf(tile[lc + 3][n]);
    *(u16x4_t*)(WT + (size_t)(nb + n) * NK + kb + lc) = o;
  }
}

// ===================== band0 staging (r7/r8 proven chunk map) =====================
// chunk(blk,kk) = 1KB: rows blk*16..+15, k kk*32..+31; lane l <-> row blk*16+(l&15),
// k +(l>>4)*8. A: chunks 0..31, B: 32..63. Groups of 16 chunks (2 loads/thread):
//  J0: A {0-7,16-23} (afL)  J1: B rel {0-3,8-11,16-19,24-27} (bfL, all wc)
//  J2: B rel {4-7,12-15,20-23,28-31} (bfH, all wc)  J3: A {8-15,24-31} (afH)
template <int J>
__device__ __forceinline__ void stage_g0(const ushort* __restrict__ A,
                                         const ushort* __restrict__ Bt,
                                         int row0, int col0, char* lds,
                                         int tau, int w, int l) {
  char* slot = lds + (tau & 1) * SLOT0_BYTES;
  const int kt = tau * BK;
#pragma unroll
  for (int q = 0; q < 2; ++q) {
    const int cg = q * 8 + w;
    if (J == 0 || J == 3) {
      const int CH = (J == 0 ? 0 : 8) + cg + (cg & 8);
      const ushort* src = A + (size_t)(row0 + (CH >> 1) * 16 + (l & 15)) * NK
                            + kt + (CH & 1) * 32 + (l >> 4) * 8;
      gload_lds16(src, slot + CH * 1024 + l * 16);
    } else {
      const int r = (cg >> 2) * 8 + (cg & 3) + (J == 2 ? 4 : 0);
      const ushort* src = Bt + (size_t)(col0 + (r >> 1) * 16 + (l & 15)) * NK
                             + kt + (r & 1) * 32 + (l >> 4) * 8;
      gload_lds16(src, slot + (32 + r) * 1024 + l * 16);
    }
  }
}

// ---------------- band0 GEMM: rows [0,4096), 256x256 tiles, 4-phase/K-tile ----------------
// MODE 0: Hout = bf16(gelu(acc+bias)); MODE 1: Yout = mask ? f32(acc+bias) : 0
template <int MODE>
__launch_bounds__(512, 2)
__global__ void gemm_b0_kernel(const ushort* __restrict__ A, const ushort* __restrict__ Bt,
                               const float* __restrict__ bias, const void* __restrict__ mask,
                               ushort* __restrict__ Hout, float* __restrict__ Yout) {
  extern __shared__ char lds[];
  const int tid = threadIdx.x;
  const int l   = tid & 63;
  const int w   = tid >> 6;
  const int wr  = w >> 2;         // 0..1: rows wr*128
  const int wc  = w & 3;          // 0..3: cols wc*64

  int bid = blockIdx.x;
  bid = (bid & 7) * (NWG0 / 8) + (bid >> 3);     // XCD swizzle, 256%8==0 bijective
  const int row0 = (bid >> 4) * BM0;
  const int col0 = (bid & 15) * BN;

  f32x4_t acc[8][4] = {};

  stage_g0<0>(A, Bt, row0, col0, lds, 0, w, l);
  stage_g0<1>(A, Bt, row0, col0, lds, 0, w, l);
  stage_g0<2>(A, Bt, row0, col0, lds, 0, w, l);
  stage_g0<3>(A, Bt, row0, col0, lds, 0, w, l);
  stage_g0<0>(A, Bt, row0, col0, lds, 1, w, l);
  stage_g0<1>(A, Bt, row0, col0, lds, 1, w, l);
  stage_g0<2>(A, Bt, row0, col0, lds, 1, w, l);
  WAIT_VM(4);                      // tile0 fully landed
  BARRIER();

  for (int t = 0; t < NT; ++t) {
    char* s = lds + (t & 1) * SLOT0_BYTES;

    // ---- P1: read afL+bfL (12), stage tile t+1 J3 ----
    bf16x8_t afL[4][2], bfL[2][2];
#pragma unroll
    for (int mi = 0; mi < 4; ++mi)
#pragma unroll
      for (int kk = 0; kk < 2; ++kk)
        afL[mi][kk] = *(const bf16x8_t*)(s + (2 * (wr * 8 + mi) + kk) * 1024 + l * 16);
#pragma unroll
    for (int ni = 0; ni < 2; ++ni)
#pragma unroll
      for (int kk = 0; kk < 2; ++kk)
        bfL[ni][kk] = *(const bf16x8_t*)(s + (32 + 2 * (wc * 4 + ni) + kk) * 1024 + l * 16);
    if (t + 1 < NT) stage_g0<3>(A, Bt, row0, col0, lds, t + 1, w, l);
    WAIT_LGKM(8);
    BARRIER();
    WAIT_LGKM(0);
    __builtin_amdgcn_s_setprio(1);
#pragma unroll
    for (int mi = 0; mi < 4; ++mi)
#pragma unroll
      for (int ni = 0; ni < 2; ++ni)
#pragma unroll
        for (int kk = 0; kk < 2; ++kk)
          acc[mi][ni] = __builtin_amdgcn_mfma_f32_16x16x32_bf16(afL[mi][kk], bfL[ni][kk],
                                                                acc[mi][ni], 0, 0, 0);
    __builtin_amdgcn_s_setprio(0);
    BARRIER();

    // ---- P2: read bfH (4), stage tile t+2 J0 ----
    bf16x8_t bfH[2][2];
#pragma unroll
    for (int ni = 0; ni < 2; ++ni)
#pragma unroll
      for (int kk = 0; kk < 2; ++kk)
        bfH[ni][kk] = *(const bf16x8_t*)(s + (32 + 2 * (wc * 4 + 2 + ni) + kk) * 1024 + l * 16);
    if (t + 2 < NT) stage_g0<0>(A, Bt, row0, col0, lds, t + 2, w, l);
    BARRIER();
    WAIT_LGKM(0);
    __builtin_amdgcn_s_setprio(1);
#pragma unroll
    for (int mi = 0; mi < 4; ++mi)
#pragma unroll
      for (int ni = 0; ni < 2; ++ni)
#pragma unroll
        for (int kk = 0; kk < 2; ++kk)
          acc[mi][2 + ni] = __builtin_amdgcn_mfma_f32_16x16x32_bf16(afL[mi][kk], bfH[ni][kk],
                                                                    acc[mi][2 + ni], 0, 0, 0);
    __builtin_amdgcn_s_setprio(0);
    BARRIER();

    // ---- P3: read afH (8), stage tile t+2 J1 ----
    bf16x8_t afH[4][2];
#pragma unroll
    for (int mi = 0; mi < 4; ++mi)
#pragma unroll
      for (int kk = 0; kk < 2; ++kk)
        afH[mi][kk] = *(const bf16x8_t*)(s + (2 * (wr * 8 + 4 + mi) + kk) * 1024 + l * 16);
    if (t + 2 < NT) stage_g0<1>(A, Bt, row0, col0, lds, t + 2, w, l);
    BARRIER();
    WAIT_LGKM(0);
    __builtin_amdgcn_s_setprio(1);
#pragma unroll
    for (int mi = 0; mi < 4; ++mi)
#pragma unroll
      for (int ni = 0; ni < 2; ++ni)
#pragma unroll
        for (int kk = 0; kk < 2; ++kk)
          acc[4 + mi][2 + ni] = __builtin_amdgcn_mfma_f32_16x16x32_bf16(afH[mi][kk], bfH[ni][kk],
                                                                        acc[4 + mi][2 + ni], 0, 0, 0);
    __builtin_amdgcn_s_setprio(0);
    BARRIER();

    // ---- P4: stage tile t+2 J2; counted vmcnt THEN barrier (global guarantee) ----
    if (t + 2 < NT) stage_g0<2>(A, Bt, row0, col0, lds, t + 2, w, l);
    if (t >= NT - 2) { WAIT_VM(0); } else { WAIT_VM(4); }
    BARRIER();
    __builtin_amdgcn_s_setprio(1);
#pragma unroll
    for (int mi = 0; mi < 4; ++mi)
#pragma unroll
      for (int ni = 0; ni < 2; ++ni)
#pragma unroll
        for (int kk = 0; kk < 2; ++kk)
          acc[4 + mi][ni] = __builtin_amdgcn_mfma_f32_16x16x32_bf16(afH[mi][kk], bfL[ni][kk],
                                                                    acc[4 + mi][ni], 0, 0, 0);
    __builtin_amdgcn_s_setprio(0);
    BARRIER();
  }

  const int isbool = (MODE == 1) ? g_mask_isbool : 0;
#pragma unroll
  for (int mi = 0; mi < 8; ++mi) {
#pragma unroll
    for (int j = 0; j < 4; ++j) {
      const int r = row0 + wr * 128 + mi * 16 + (l >> 4) * 4 + j;
      if (MODE == 0) {
#pragma unroll
        for (int ni = 0; ni < 4; ++ni) {
          const int c = col0 + wc * 64 + ni * 16 + (l & 15);
          float v = acc[mi][ni][j] + bias[c];
          v = 0.5f * v * (1.0f + erff(v * 0.70710678118654752f));
          Hout[(size_t)r * NK + c] = f2bf(v);
        }
      } else {
        const int bb  = (r >= ROWS_PB) ? 1 : 0;
        const int idx = bb * S_TOK + P_TOK + (r - bb * ROWS_PB);
        const int mk  = isbool ? (int)((const unsigned char*)mask)[idx]
                               : ((const int*)mask)[idx];
#pragma unroll
        for (int ni = 0; ni < 4; ++ni) {
          const int c = col0 + wc * 64 + ni * 16 + (l & 15);
          const float v = acc[mi][ni][j] + bias[c];
          Yout[(size_t)r * NK + c] = mk ? v : 0.0f;
        }
      }
    }
  }
}

// ===================== band1 staging (RACE-FIXED grouping) =====================
// Slot 48KB: A chunks 0..15 (128 rows), B chunks 16..47 (rel 0..31).
// Groups (16 chunks, 2/thread):
//   J0 = A all (af, all wr)
//   J1 = B rel {0-3,8-11,16-19,24-27} (bfL for ALL wc)   <- was sequential: race
//   J2 = B rel {4-7,12-15,20-23,28-31} (bfH for ALL wc)
template <int J>
__device__ __forceinline__ void stage_g1(const ushort* __restrict__ A,
                                         const ushort* __restrict__ Bt,
                                         int row0, int col0, char* lds,
                                         int tau, int w, int l) {
  char* slot = lds + (tau & 1) * SLOT1_BYTES;
  const int kt = tau * BK;
#pragma unroll
  for (int q = 0; q < 2; ++q) {
    const int cg = q * 8 + w;     // 0..15
    if (J == 0) {
      const ushort* src = A + (size_t)(row0 + (cg >> 1) * 16 + (l & 15)) * NK
                            + kt + (cg & 1) * 32 + (l >> 4) * 8;
      gload_lds16(src, slot + cg * 1024 + l * 16);
    } else {
      const int r = (cg >> 2) * 8 + (cg & 3) + (J == 2 ? 4 : 0);
      const ushort* src = Bt + (size_t)(col0 + (r >> 1) * 16 + (l & 15)) * NK
                             + kt + (r & 1) * 32 + (l >> 4) * 8;
      gload_lds16(src, slot + (16 + r) * 1024 + l * 16);
    }
  }
}

// ---------------- band1 GEMM: rows [4096,6144), 128x256 tiles, 2-phase/K-tile ----------------
// FIFO proof (2 loads per group-stage, per thread):
//   prologue: J0(0),J1(0),J2(0),J0(1),J1(1) = 10; WAIT_VM(6) -> J0,J1(0) landed; BARRIER.
//   steady, entering P1(t): [J2(t),J0(t+1),J1(t+1)]=6. P1 stages J2(t+1) -> 8;
//     end-P1 WAIT_VM(6) -> J2(t) landed (for P2 reads); BARRIER.
//   P2 stages J0,J1(t+2) -> 10; end-P2 WAIT_VM(6) -> J0,J1(t+1) landed (next P1); BARRIER.
//   tail: end-P2@t=NT-2 and end-P1@t=NT-1 use WAIT_VM(0).
template <int MODE>
__launch_bounds__(512, 2)
__global__ void gemm_b1_kernel(const ushort* __restrict__ A, const ushort* __restrict__ Bt,
                               const float* __restrict__ bias, const void* __restrict__ mask,
                               ushort* __restrict__ Hout, float* __restrict__ Yout) {
  extern __shared__ char lds[];
  const int tid = threadIdx.x;
  const int l   = tid & 63;
  const int w   = tid >> 6;
  const int wr  = w >> 2;         // 0..1: rows wr*64
  const int wc  = w & 3;          // 0..3: cols wc*64

  int bid = blockIdx.x;
  bid = (bid & 7) * (NWG1 / 8) + (bid >> 3);
  const int row0 = ROW_BASE1 + (bid >> 4) * BM1;
  const int col0 = (bid & 15) * BN;

  f32x4_t acc[4][4] = {};

  stage_g1<0>(A, Bt, row0, col0, lds, 0, w, l);
  stage_g1<1>(A, Bt, row0, col0, lds, 0, w, l);
  stage_g1<2>(A, Bt, row0, col0, lds, 0, w, l);
  stage_g1<0>(A, Bt, row0, col0, lds, 1, w, l);
  stage_g1<1>(A, Bt, row0, col0, lds, 1, w, l);
  WAIT_VM(6);                      // J0(0),J1(0) landed
  BARRIER();

  for (int t = 0; t < NT; ++t) {
    char* s = lds + (t & 1) * SLOT1_BYTES;

    // ---- P1: read af (8) + bfL (4); stage tile t+1 J2 ----
    bf16x8_t af[4][2], bfL[2][2];
#pragma unroll
    for (int mi = 0; mi < 4; ++mi)
#pragma unroll
      for (int kk = 0; kk < 2; ++kk)
        af[mi][kk] = *(const bf16x8_t*)(s + ((wr * 4 + mi) * 2 + kk) * 1024 + l * 16);
#pragma unroll
    for (int ni = 0; ni < 2; ++ni)
#pragma unroll
      for (int kk = 0; kk < 2; ++kk)
        bfL[ni][kk] = *(const bf16x8_t*)(s + (16 + (wc * 4 + ni) * 2 + kk) * 1024 + l * 16);
    if (t + 1 < NT) stage_g1<2>(A, Bt, row0, col0, lds, t + 1, w, l);
    WAIT_LGKM(8);
    BARRIER();
    WAIT_LGKM(0);
    __builtin_amdgcn_s_setprio(1);
#pragma unroll
    for (int mi = 0; mi < 4; ++mi)
#pragma unroll
      for (int ni = 0; ni < 2; ++ni)
#pragma unroll
        for (int kk = 0; kk < 2; ++kk)
          acc[mi][ni] = __builtin_amdgcn_mfma_f32_16x16x32_bf16(af[mi][kk], bfL[ni][kk],
                                                                acc[mi][ni], 0, 0, 0);
    __builtin_amdgcn_s_setprio(0);
    // end-P1: guarantee J2(t) (bfH data) before any wave's P2 reads
    if (t == NT - 1) { WAIT_VM(0); } else { WAIT_VM(6); }
    BARRIER();

    // ---- P2: read bfH (4); stage tile t+2 J0,J1 ----
    bf16x8_t bfH[2][2];
#pragma unroll
    for (int ni = 0; ni < 2; ++ni)
#pragma unroll
      for (int kk = 0; kk < 2; ++kk)
        bfH[ni][kk] = *(const bf16x8_t*)(s + (16 + (wc * 4 + 2 + ni) * 2 + kk) * 1024 + l * 16);
    if (t + 2 < NT) {
      stage_g1<0>(A, Bt, row0, col0, lds, t + 2, w, l);
      stage_g1<1>(A, Bt, row0, col0, lds, t + 2, w, l);
    }
    BARRIER();
    WAIT_LGKM(0);
    __builtin_amdgcn_s_setprio(1);
#pragma unroll
    for (int mi = 0; mi < 4; ++mi)
#pragma unroll
      for (int ni = 0; ni < 2; ++ni)
#pragma unroll
        for (int kk = 0; kk < 2; ++kk)
          acc[mi][2 + ni] = __builtin_amdgcn_mfma_f32_16x16x32_bf16(af[mi][kk], bfH[ni][kk],
                                                                    acc[mi][2 + ni], 0, 0, 0);
    __builtin_amdgcn_s_setprio(0);
    // end-P2: guarantee J0,J1(t+1) (af/bfL data) before next iteration's P1 reads
    if (t >= NT - 2) { WAIT_VM(0); } else { WAIT_VM(6); }
    BARRIER();
  }

  const int isbool = (MODE == 1) ? g_mask_isbool : 0;
#pragma unroll
  for (int mi = 0; mi < 4; ++mi) {
#pragma unroll
    for (int j = 0; j < 4; ++j) {
      const int r = row0 + wr * 64 + mi * 16 + (l >> 4) * 4 + j;
      if (MODE == 0) {
#pragma unroll
        for (int ni = 0; ni < 4; ++ni) {
          const int c = col0 + wc * 64 + ni * 16 + (l & 15);
          float v = acc[mi][ni][j] + bias[c];
          v = 0.5f * v * (1.0f + erff(v * 0.70710678118654752f));
          Hout[(size_t)r * NK + c] = f2bf(v);
        }
      } else {
        const int bb  = (r >= ROWS_PB) ? 1 : 0;
        const int idx = bb * S_TOK + P_TOK + (r - bb * ROWS_PB);
        const int mk  = isbool ? (int)((const unsigned char*)mask)[idx]
                               : ((const int*)mask)[idx];
#pragma unroll
        for (int ni = 0; ni < 4; ++ni) {
          const int c = col0 + wc * 64 + ni * 16 + (l & 15);
          const float v = acc[mi][ni][j] + bias[c];
          Yout[(size_t)r * NK + c] = mk ? v : 0.0f;
        }
      }
    }
  }
}

extern "C" void kernel_launch(void* const* d_in, const int* in_sizes, int n_in,
                              void* d_out, int out_size, void* d_ws, size_t ws_size,
                              hipStream_t stream) {
  const float* x     = (const float*)d_in[0];
  const void*  tmask = (const void*)d_in[1];
  // d_in[2] = prefix_mask (shape known: prefix_len = 4096 rows dropped)
  const float* W1    = (const float*)d_in[3];
  const float* b1    = (const float*)d_in[4];
  const float* W2    = (const float*)d_in[5];
  const float* b2    = (const float*)d_in[6];
  float* out = (float*)d_out;   // reference output dtype is float32

  const size_t offA1  = 0;
  const size_t offB1T = offA1  + (size_t)M_ROWS * NK * 2;   // 48 MiB
  const size_t offB2T = offB1T + (size_t)NK * NK * 2;       // +32 MiB
  const size_t offH   = offB2T + (size_t)NK * NK * 2;       // +32 MiB
  const size_t need   = offH   + (size_t)M_ROWS * NK * 2;   // +48 MiB = 160 MiB
  if (ws_size < need) return;

  char* ws = (char*)d_ws;
  ushort* A1  = (ushort*)(ws + offA1);
  ushort* B1T = (ushort*)(ws + offB1T);
  ushort* B2T = (ushort*)(ws + offB2T);
  ushort* H   = (ushort*)(ws + offH);

  detect_mask_kernel<<<1, 64, 0, stream>>>((const unsigned*)tmask);
  convert_x_kernel<<<dim3(M_ROWS), 256, 0, stream>>>(x, A1);
  transpose_w_kernel<<<dim3(64, 64), 256, 0, stream>>>(W1, B1T);
  transpose_w_kernel<<<dim3(64, 64), 256, 0, stream>>>(W2, B2T);
  gemm_b0_kernel<0><<<dim3(NWG0), dim3(512), LDS0_TOTAL, stream>>>(A1, B1T, b1, nullptr, H, nullptr);
  gemm_b1_kernel<0><<<dim3(NWG1), dim3(512), LDS1_TOTAL, stream>>>(A1, B1T, b1, nullptr, H, nullptr);
  gemm_b0_kernel<1><<<dim3(NWG0), dim3(512), LDS0_TOTAL, stream>>>(H, B2T, b2, tmask, nullptr, out);
  gemm_b1_kernel<1><<<dim3(NWG1), dim3(512), LDS1_TOTAL, stream>>>(H, B2T, b2, tmask, nullptr, out);
}